// Round 14
// baseline (320.277 us; speedup 1.0000x reference)
//
#include <hip/hip_runtime.h>
#include <hip/hip_bf16.h>

// ---------------------------------------------------------------------------
// Sparse conv backbone, bf16 MFMA, round 24 = hybrid LDS+VGPR gather pipeline
// for enc1 + prologue divide fix.
// r23 verdict: XCD swizzle ~3us (locality minor). Six enc1 variants all pin
// in-flight gather bytes at the LDS cap (~115KB/CU) -> same ~2.6 TB/s. r20's
// WEIGHTS proved VGPR loads pipeline fine under strict queue order + counted
// vmcnt. r24 enc1 (MT=4): even K-chunks -> 2 LDS-DMA slots (as r23), odd
// K-chunks -> 2 VGPR stages (16 VGPR each), one strict stage-ordered queue,
// depth 4 (256 rows/wave in flight, ~2x). Exact waits: vmcnt(14) iters 0-1,
// vmcnt(6) after; dummy tail refills keep counts uniform (asm keep-alives).
// launch_bounds (256,3) for MT=4 (BNF worst ~139 VGPR < 170; grid gives 3.58
// blocks/CU anyway). enc2/conv2 path byte-identical to r23. Prologue: runtime
// /CIN,%CIN,/NT -> shifts (powers of 2). r23: 306.9us, absmax 0.109.
// ---------------------------------------------------------------------------

typedef float f4 __attribute__((ext_vector_type(4)));
typedef short short8 __attribute__((ext_vector_type(8)));
typedef short short4v __attribute__((ext_vector_type(4)));

#define BN_EPS 1e-5f

static inline int ceil_div(int a, int b) { return (a + b - 1) / b; }

static __device__ inline float btof(short s) {
    unsigned u = ((unsigned)(unsigned short)s) << 16;
    float f;
    __builtin_memcpy(&f, &u, 4);
    return f;
}
static __device__ inline short ftob(float f) {
    __hip_bfloat16 h = __float2bfloat16(f);
    short s;
    __builtin_memcpy(&s, &h, 2);
    return s;
}

// bijective XCD-aware swizzle (m204 form)
static __device__ inline int xcd_swz(int b, int nwg) {
    int q = nwg >> 3, rr = nwg & 7;
    int xcd = b & 7, pos = b >> 3;
    return (xcd < rr) ? (xcd * (q + 1) + pos)
                      : (rr * (q + 1) + (xcd - rr) * q + pos);
}

// async 16B global->LDS (per-lane global addr; wave-uniform LDS base)
static __device__ inline void gl_lds16(const void* g, void* l) {
    __builtin_amdgcn_global_load_lds(
        (const __attribute__((address_space(1))) void*)g,
        (__attribute__((address_space(3))) void*)l, 16, 0, 0);
}

template <int N>
static __device__ inline void s_wait_vmcnt() {
    if constexpr (N == 0) asm volatile("s_waitcnt vmcnt(0)" ::: "memory");
    else if constexpr (N == 6) asm volatile("s_waitcnt vmcnt(6)" ::: "memory");
    else if constexpr (N == 9) asm volatile("s_waitcnt vmcnt(9)" ::: "memory");
    else if constexpr (N == 14) asm volatile("s_waitcnt vmcnt(14)" ::: "memory");
    else if constexpr (N == 18) asm volatile("s_waitcnt vmcnt(18)" ::: "memory");
    else if constexpr (N == 8) asm volatile("s_waitcnt vmcnt(8)" ::: "memory");
    else asm volatile("s_waitcnt vmcnt(4)" ::: "memory");
}

struct Seg {
    const float* W;
    long long begin, end;
    int K, CIN, COUT, lgc, lgnt;
};

struct ProArgs {
    Seg s[10];
    const float* geo;
    const float* col;
    __hip_bfloat16* x0;
    int n_vox;
    float* stats;
    __hip_bfloat16* pads[5];
    int padn[5];
    long long wf_total;
    long long pro_total;
    __hip_bfloat16* Wf;
    const int* m1;
    __hip_bfloat16* A;
    int nc2;
};

// ---------------- BN coefficient helper (NS slots: 8 for C=32, 4 for C=64) --
template <int C>
__device__ inline void bn_coef(const float* st, const float* g, const float* b,
                               int c, int n, float& sc, float& sh) {
    constexpr int NS = (C == 32) ? 8 : 4;
    float rn = 1.f / (float)n;
    float sum = 0.f, sq = 0.f;
#pragma unroll
    for (int s = 0; s < NS; ++s) {
        sum += st[(s * 2 + 0) * C + c];
        sq  += st[(s * 2 + 1) * C + c];
    }
    float mu = sum * rn;
    float inv = rsqrtf(sq * rn - mu * mu + BN_EPS);
    sc = inv * g[c];
    sh = b[c] - mu * sc;
}

// ---------------- prologue: pack weights + build x0 + zero stats/pads -------
__global__ __launch_bounds__(256) void k_prologue(ProArgs pa) {
    for (long long e = (long long)blockIdx.x * 256 + threadIdx.x; e < pa.pro_total;
         e += (long long)gridDim.x * 256) {
        if (e < pa.wf_total) {
            int si = 0;
#pragma unroll
            for (int i = 0; i < 10; ++i)
                if (e >= pa.s[i].end) si = i + 1;
            const Seg sg = pa.s[si];
            long long r = e - sg.begin;
            int j = (int)(r & 7);
            int lane = (int)((r >> 3) & 63);
            long long rest = r >> 9;
            int ntile = (int)(rest & ((1 << sg.lgnt) - 1));
            int chunk = (int)(rest >> sg.lgnt);
            int kd = chunk * 32 + ((lane >> 4) << 3) + j;
            int koff = kd >> sg.lgc;
            int ci = kd & (sg.CIN - 1);
            int n = ntile * 16 + (lane & 15);
            float v = (koff < sg.K) ? sg.W[((size_t)koff * sg.CIN + ci) * sg.COUT + n] : 0.f;
            pa.Wf[e] = __float2bfloat16(v);
            continue;
        }
        long long r = e - pa.wf_total;
        if (r < pa.n_vox) {
            int row = (int)r;
            pa.x0[row * 4 + 0] = __float2bfloat16(pa.geo[row]);
            pa.x0[row * 4 + 1] = __float2bfloat16(pa.col[row * 3 + 0]);
            pa.x0[row * 4 + 2] = __float2bfloat16(pa.col[row * 3 + 1]);
            pa.x0[row * 4 + 3] = __float2bfloat16(pa.col[row * 3 + 2]);
            continue;
        }
        r -= pa.n_vox;
        if (r < 4096) {
            pa.stats[r] = 0.f;
            continue;
        }
        r -= 4096;
#pragma unroll
        for (int i = 0; i < 5; ++i) {
            if (r < pa.padn[i]) {
                pa.pads[i][r] = __float2bfloat16(0.f);
                r = -1;
                break;
            }
            r -= pa.padn[i];
        }
    }
}

// ---------------- stem conv (CIN=4, COUT=32, K=125->128, relu) --------------
__global__ __launch_bounds__(256) void k_stem(ProArgs a) {
    const int t = threadIdx.x, w = t >> 6, lane = t & 63;
    const int quad = lane >> 4, ml = lane & 15;
    const int ntile = w & 1, mgroup = w >> 1;
    const int n_out = a.nc2, n_in = a.n_vox;
    const __hip_bfloat16* feat = a.x0;
    const __hip_bfloat16* Wf = a.Wf;   // stem at offset 0
    const int* in_map = a.m1;
    __hip_bfloat16* out = a.A;
    const int mb = blockIdx.x * 64 + mgroup * 32;
    const int m0 = mb + ml, m1 = mb + 16 + ml;
    const bool v0 = m0 < n_out, v1 = m1 < n_out;
    f4 acc0 = {0.f, 0.f, 0.f, 0.f};
    f4 acc1 = {0.f, 0.f, 0.f, 0.f};
#pragma unroll 2
    for (int chunk = 0; chunk < 16; ++chunk) {
        int k0 = chunk * 8 + quad * 2;
        int k1 = k0 + 1;
        int k0c = (k0 < 125) ? k0 : 0;   // weights zero for k>=125
        int k1c = (k1 < 125) ? k1 : 0;
        short8 b = *(const short8*)(Wf + ((size_t)(chunk * 2 + ntile) * 64 + lane) * 8);
        int ia = v0 ? in_map[(size_t)k0c * n_out + m0] : n_in;
        int ib = v0 ? in_map[(size_t)k1c * n_out + m0] : n_in;
        int ic = v1 ? in_map[(size_t)k0c * n_out + m1] : n_in;
        int id = v1 ? in_map[(size_t)k1c * n_out + m1] : n_in;
        short4v p0 = *(const short4v*)(feat + (size_t)ia * 4);
        short4v p1 = *(const short4v*)(feat + (size_t)ib * 4);
        short4v p2 = *(const short4v*)(feat + (size_t)ic * 4);
        short4v p3 = *(const short4v*)(feat + (size_t)id * 4);
        short8 a0, a1;
        a0[0] = p0[0]; a0[1] = p0[1]; a0[2] = p0[2]; a0[3] = p0[3];
        a0[4] = p1[0]; a0[5] = p1[1]; a0[6] = p1[2]; a0[7] = p1[3];
        a1[0] = p2[0]; a1[1] = p2[1]; a1[2] = p2[2]; a1[3] = p2[3];
        a1[4] = p3[0]; a1[5] = p3[1]; a1[6] = p3[2]; a1[7] = p3[3];
        acc0 = __builtin_amdgcn_mfma_f32_16x16x32_bf16(a0, b, acc0, 0, 0, 0);
        acc1 = __builtin_amdgcn_mfma_f32_16x16x32_bf16(a1, b, acc1, 0, 0, 0);
    }
    const int col = ntile * 16 + ml;
#pragma unroll
    for (int i = 0; i < 4; ++i) {
        int r0 = mb + quad * 4 + i;
        if (r0 < n_out)
            out[(size_t)r0 * 32 + col] = __float2bfloat16(fmaxf(acc0[i], 0.f));
        int r1 = mb + 16 + quad * 4 + i;
        if (r1 < n_out)
            out[(size_t)r1 * 32 + col] = __float2bfloat16(fmaxf(acc1[i], 0.f));
    }
}

// ---------------- async conv: MT=1 -> r23 D=2 LDS path; MT=4 -> hybrid ------
template <int CIN, int COUT, int MT, int K, bool BNF>
__global__ __launch_bounds__(256, (CIN == 64 || MT == 4) ? 3 : 4)
void k_conv(
    const __hip_bfloat16* __restrict__ feat,
    const __hip_bfloat16* __restrict__ Wf,
    const int* __restrict__ in_map,
    __hip_bfloat16* __restrict__ out,
    float* __restrict__ stats,
    const float* __restrict__ in_stats,
    const float* __restrict__ in_g,
    const float* __restrict__ in_b,
    int n_out, int n_in) {
    constexpr int NT = COUT / 16;
    constexpr int H = CIN / 32;
    constexpr int R = MT * 16;
    constexpr int KPW = (K + 3) / 4;
    constexpr int SP = COUT + 1;
    constexpr int S = CIN / 8;             // 16B slices per feature row
    constexpr int SW = (S == 4) ? 1 : 0;   // swizzle row-shift (bank-class fix)
    constexpr int RPI = 64 / S;            // rows per gload instr (1KB each)
    constexpr int NI = R / RPI;            // gload instrs per stage
    constexpr int NB = H * NT;             // bfrag 16B loads per stage
    constexpr int D = 2;                   // LDS slot count
    constexpr int WAIT_N = NI + 2 * NB;    // MT=1 path: enc2 18, conv2 9
    constexpr int NSLOT = (COUT == 32) ? 8 : 4;
    constexpr int STAGE_B = R * CIN * 2;
    constexpr int STAGE_TOT = 4 * D * STAGE_B;
    constexpr int RED_B = 4 * R * SP * 4;
    constexpr int UNION_B = (STAGE_TOT > RED_B) ? STAGE_TOT : RED_B;
    constexpr bool HYB = (MT == 4);
    static_assert(!HYB || (NI == 4 && NB == 2 && H == 1 && KPW == 7),
                  "hybrid schedule assumes enc1 shape");

    __shared__ char smem[UNION_B + 2048 + 512];
    float* red  = (float*)smem;
    float* sred = (float*)(smem + UNION_B);
    float* ibn  = (float*)(smem + UNION_B + 2048);

    const int t = threadIdx.x, w = t >> 6, lane = t & 63;
    const int quad = lane >> 4, ml = lane & 15;
    const int wb = xcd_swz((int)blockIdx.x, (int)gridDim.x);
    const int mb = wb * R;
    char* stw = smem + w * (D * STAGE_B);
    const int srow = lane / S;
    const int ssl = lane & (S - 1);

    if constexpr (BNF) {
        if (t < CIN) {
            float sc, sh;
            bn_coef<CIN>(in_stats, in_g, in_b, t, n_in, sc, sh);
            ibn[t] = sc;
            ibn[CIN + t] = sh;
        }
        __syncthreads();
    }
    float scr[H][8], shr[H][8];
    if constexpr (BNF) {
#pragma unroll
        for (int h = 0; h < H; ++h)
#pragma unroll
            for (int j = 0; j < 8; ++j) {
                int ch = h * 32 + quad * 8 + j;
                scr[h][j] = ibn[ch];
                shr[h][j] = ibn[CIN + ch];
            }
    }

    f4 acc[MT * NT];
#pragma unroll
    for (int i = 0; i < MT * NT; ++i) acc[i] = (f4){0.f, 0.f, 0.f, 0.f};

    if constexpr (HYB) {
        // ================= hybrid LDS+VGPR pipeline (enc1) =================
        // even kk -> LDS slots (2); odd kk -> VGPR stages (2). Stage depth 4,
        // weights depth 2, all in strict vmcnt queue order.
        int sidx[4][NI];   // even taps kk=0,2,4,6 (srow layout)
        int vidx[3][MT];   // odd taps kk=1,3,5 (per-lane mi layout)
#pragma unroll
        for (int e = 0; e < 4; ++e) {
            const int k = (2 * e) * 4 + w;
            const int krow = (k < K) ? k : 0;
            const int* mk = in_map + (size_t)krow * n_out;
#pragma unroll
            for (int inst = 0; inst < NI; ++inst) {
                int m = mb + inst * RPI + srow;
                sidx[e][inst] = (m < n_out) ? mk[m] : n_in;
            }
        }
#pragma unroll
        for (int o = 0; o < 3; ++o) {
            const int k = (2 * o + 1) * 4 + w;
            const int krow = (k < K) ? k : 0;
            const int* mk = in_map + (size_t)krow * n_out;
#pragma unroll
            for (int mi = 0; mi < MT; ++mi) {
                int m = mb + mi * 16 + ml;
                vidx[o][mi] = (m < n_out) ? mk[m] : n_in;
            }
        }

        short8 vs0[MT], vs1[MT];
        short8 bf0[NB], bf1[NB];

        auto issue_S = [&](int e, int slot) {
#pragma unroll
            for (int inst = 0; inst < NI; ++inst) {
                int rg = inst * RPI + srow;
                int gsl = ssl ^ ((rg >> SW) & (S - 1));
                const __hip_bfloat16* src =
                    feat + (size_t)sidx[e][inst] * CIN + gsl * 8;
                gl_lds16(src, stw + slot * STAGE_B + inst * 1024);
            }
        };
        auto issue_V = [&](int o, short8 (&vs)[MT]) {
#pragma unroll
            for (int mi = 0; mi < MT; ++mi)
                vs[mi] = *(const short8*)(
                    feat + (size_t)vidx[o][mi] * CIN + quad * 8);
        };
        auto issue_B = [&](int kk, short8 (&bfc)[NB]) {
            const int k = kk * 4 + w;
#pragma unroll
            for (int h = 0; h < H; ++h)
#pragma unroll
                for (int nt = 0; nt < NT; ++nt)
                    bfc[h * NT + nt] = *(const short8*)(
                        Wf + (((size_t)(k * H + h) * NT + nt) * 64 + lane) * 8);
        };
        auto mfma_row = [&](int mi, short8 a, short8 (&bfc)[NB], bool sent) {
            if constexpr (BNF) {
#pragma unroll
                for (int j = 0; j < 8; ++j) {
                    float f = btof(a[j]) * scr[0][j] + shr[0][j];
                    f = fmaxf(f, 0.f);
                    a[j] = sent ? (short)0 : ftob(f);
                }
            }
            (void)sent;
#pragma unroll
            for (int nt = 0; nt < NT; ++nt)
                acc[mi * NT + nt] = __builtin_amdgcn_mfma_f32_16x16x32_bf16(
                    a, bfc[nt], acc[mi * NT + nt], 0, 0, 0);
        };

        // prologue (strict need-order): S0 B0 V1 B1 S2 V3
        issue_S(0, 0);
        issue_B(0, bf0);
        issue_V(0, vs0);
        issue_B(1, bf1);
        issue_S(1, 1);
        issue_V(1, vs1);
        __builtin_amdgcn_sched_barrier(0);

#pragma unroll
        for (int kk = 0; kk < 7; ++kk) {
            if (kk < 2) s_wait_vmcnt<14>(); else s_wait_vmcnt<6>();
            __builtin_amdgcn_sched_barrier(0);

            if ((kk & 1) == 0) {
                const int e = kk >> 1;
                const int slot = e & 1;
                int cidx[MT];
                if constexpr (BNF) {
#pragma unroll
                    for (int mi = 0; mi < MT; ++mi)
                        cidx[mi] = __shfl(sidx[e][mi], ml * S);
                }
#pragma unroll
                for (int mi = 0; mi < MT; ++mi) {
                    const int p = quad ^ ((ml >> SW) & (S - 1));
                    short8 a = *(const short8*)(
                        stw + slot * STAGE_B + ((mi * 16 + ml) * CIN + p * 8) * 2);
                    bool sent = false;
                    if constexpr (BNF) sent = (cidx[mi] == n_in);
                    if (kk & 1) mfma_row(mi, a, bf1, sent);
                    else        mfma_row(mi, a, bf0, sent);
                }
            } else {
                const int o = kk >> 1;
#pragma unroll
                for (int mi = 0; mi < MT; ++mi) {
                    short8 a = (o & 1) ? vs1[mi] : vs0[mi];
                    bool sent = false;
                    if constexpr (BNF) sent = (vidx[o][mi] == n_in);
                    mfma_row(mi, a, bf1, sent);
                }
            }

            __builtin_amdgcn_sched_barrier(0);
            // issue stage kk+4 (matching type/slot) + weights kk+2
            const int nk = kk + 4;
            if ((nk & 1) == 0) {
                issue_S((nk <= 6) ? (nk >> 1) : 0, (nk >> 1) & 1);
            } else {
                const int no = (nk <= 5) ? (nk >> 1) : 0;
                if ((nk >> 1) & 1) issue_V(no, vs1); else issue_V(no, vs0);
            }
            const int nbk = (kk + 2 <= 6) ? (kk + 2) : 0;
            if ((kk + 2) & 1) issue_B(nbk, bf1); else issue_B(nbk, bf0);
            __builtin_amdgcn_sched_barrier(0);
        }

#pragma unroll
        for (int i = 0; i < NB; ++i) {
            asm volatile("" ::"v"(bf0[i]));
            asm volatile("" ::"v"(bf1[i]));
        }
#pragma unroll
        for (int i = 0; i < MT; ++i) {
            asm volatile("" ::"v"(vs0[i]));
            asm volatile("" ::"v"(vs1[i]));
        }
        s_wait_vmcnt<0>();
        __syncthreads();
    } else {
        // ================= r23 D=2 LDS path (MT=1: enc2/conv2) =============
        int idxs[KPW][NI];
#pragma unroll
        for (int kk = 0; kk < KPW; ++kk) {
            const int k = kk * 4 + w;
            const int krow = (k < K) ? k : 0;
            const int* mk = in_map + (size_t)krow * n_out;
#pragma unroll
            for (int inst = 0; inst < NI; ++inst) {
                int m = mb + inst * RPI + srow;
                idxs[kk][inst] = (m < n_out) ? mk[m] : n_in;
            }
        }

        short8 bf0[NB], bf1[NB];

        auto issue_stage = [&](int stg, int slot) {
#pragma unroll
            for (int inst = 0; inst < NI; ++inst) {
                int rg = inst * RPI + srow;
                int gsl = ssl ^ ((rg >> SW) & (S - 1));
                const __hip_bfloat16* src =
                    feat + (size_t)idxs[stg][inst] * CIN + gsl * 8;
                gl_lds16(src, stw + slot * STAGE_B + inst * 1024);
            }
        };
        auto issue_bf = [&](int stg, short8 (&bfc)[NB]) {
            const int k = stg * 4 + w;
#pragma unroll
            for (int h = 0; h < H; ++h)
#pragma unroll
                for (int nt = 0; nt < NT; ++nt)
                    bfc[h * NT + nt] = *(const short8*)(
                        Wf + (((size_t)(k * H + h) * NT + nt) * 64 + lane) * 8);
        };

        issue_stage(0, 0);
        issue_bf(0, bf0);
        issue_stage(1, 1);
        issue_bf(1, bf1);
        __builtin_amdgcn_sched_barrier(0);

#pragma unroll
        for (int kk = 0; kk < KPW; ++kk) {
            s_wait_vmcnt<WAIT_N>();
            __builtin_amdgcn_sched_barrier(0);

            const int slot = kk & 1;
            short8 (&bfc)[NB] = (kk & 1) ? bf1 : bf0;

            int cidx[MT];
            if constexpr (BNF) {
#pragma unroll
                for (int mi = 0; mi < MT; ++mi) {
                    if constexpr (RPI >= 16) {
                        cidx[mi] = __shfl(idxs[kk][(mi * 16) / RPI], ml * S);
                    } else {
                        int a0 = __shfl(idxs[kk][0], (ml & 7) * S);
                        int a1 = __shfl(idxs[kk][NI - 1], (ml & 7) * S);
                        cidx[mi] = (ml < 8) ? a0 : a1;
                    }
                }
            }

#pragma unroll
            for (int mi = 0; mi < MT; ++mi) {
#pragma unroll
                for (int h = 0; h < H; ++h) {
                    const int p = (h * 4 + quad) ^ ((ml >> SW) & (S - 1));
                    short8 a = *(const short8*)(
                        stw + slot * STAGE_B + ((mi * 16 + ml) * CIN + p * 8) * 2);
                    if constexpr (BNF) {
                        const bool sent = (cidx[mi] == n_in);
#pragma unroll
                        for (int j = 0; j < 8; ++j) {
                            float f = btof(a[j]) * scr[h][j] + shr[h][j];
                            f = fmaxf(f, 0.f);
                            a[j] = sent ? (short)0 : ftob(f);
                        }
                    }
#pragma unroll
                    for (int nt = 0; nt < NT; ++nt)
                        acc[mi * NT + nt] = __builtin_amdgcn_mfma_f32_16x16x32_bf16(
                            a, bfc[h * NT + nt], acc[mi * NT + nt], 0, 0, 0);
                }
            }

            __builtin_amdgcn_sched_barrier(0);
            const int ns = (kk + 2 < KPW) ? (kk + 2) : 0;
            issue_stage(ns, slot);
            if (kk & 1) issue_bf(ns, bf1); else issue_bf(ns, bf0);
            __builtin_amdgcn_sched_barrier(0);
        }

#pragma unroll
        for (int i = 0; i < NB; ++i) {
            asm volatile("" ::"v"(bf0[i]));
            asm volatile("" ::"v"(bf1[i]));
        }
        s_wait_vmcnt<0>();
        __syncthreads();
    }

#pragma unroll
    for (int mi = 0; mi < MT; ++mi)
#pragma unroll
        for (int nt = 0; nt < NT; ++nt)
#pragma unroll
            for (int i = 0; i < 4; ++i)
                red[((size_t)w * R + mi * 16 + quad * 4 + i) * SP + nt * 16 + ml] =
                    acc[mi * NT + nt][i];
    __syncthreads();

    constexpr int E = (R * COUT) / 256;
    constexpr int RSTEP = 256 / COUT;
    const int col = t % COUT;
    const int rg = t / COUT;
    float s = 0.f, s2 = 0.f;
#pragma unroll
    for (int i = 0; i < E; ++i) {
        int r = rg + i * RSTEP;
        float v = red[(0 * R + r) * SP + col] + red[(1 * R + r) * SP + col] +
                  red[(2 * R + r) * SP + col] + red[(3 * R + r) * SP + col];
        s += v;
        s2 += v * v;
        int grow = mb + r;
        if (grow < n_out) out[(size_t)grow * COUT + col] = __float2bfloat16(v);
    }

    if (stats) {
        sred[t] = s;
        sred[256 + t] = s2;
        __syncthreads();
        if (t < 2 * COUT) {
            int c = t % COUT;
            int which = t / COUT;   // 0 = sum, 1 = sumsq
            float v = 0.f;
#pragma unroll
            for (int j = 0; j < RSTEP; ++j) v += sred[which * 256 + j * COUT + c];
            atomicAdd(&stats[((wb & (NSLOT - 1)) * 2 + which) * COUT + c], v);
        }
    }
}

// ---------------- BN residual apply ----------------
template <int C, bool F32OUT>
__global__ __launch_bounds__(256) void k_bnres(
    const __hip_bfloat16* __restrict__ y, const __hip_bfloat16* __restrict__ res,
    const float* __restrict__ st, const float* __restrict__ g,
    const float* __restrict__ b, void* outp, int n) {
    __shared__ float ibn[2 * C];
    const int t = threadIdx.x;
    if (t < C) {
        float sc, sh;
        bn_coef<C>(st, g, b, t, n, sc, sh);
        ibn[t] = sc;
        ibn[C + t] = sh;
    }
    __syncthreads();
    long long tot = (long long)n * (C / 8);
    long long i = (long long)blockIdx.x * 256 + t;
    if (i >= tot) return;
    int c0 = (int)(i % (C / 8)) * 8;
    short8 v = *(const short8*)(y + i * 8);
    short8 r = *(const short8*)(res + i * 8);
    if constexpr (F32OUT) {
        float* out = (float*)outp;
        f4 o0, o1;
#pragma unroll
        for (int j = 0; j < 8; ++j) {
            float f = btof(v[j]) * ibn[c0 + j] + ibn[C + c0 + j] + btof(r[j]);
            f = fmaxf(f, 0.f);
            if (j < 4) o0[j] = f; else o1[j - 4] = f;
        }
        *(f4*)(out + i * 8) = o0;
        *(f4*)(out + i * 8 + 4) = o1;
    } else {
        __hip_bfloat16* out = (__hip_bfloat16*)outp;
        short8 o;
#pragma unroll
        for (int j = 0; j < 8; ++j) {
            float f = btof(v[j]) * ibn[c0 + j] + ibn[C + c0 + j] + btof(r[j]);
            o[j] = ftob(fmaxf(f, 0.f));
        }
        *(short8*)(out + i * 8) = o;
    }
}

// ---------------------------------------------------------------------------
extern "C" void kernel_launch(void* const* d_in, const int* in_sizes, int n_in_cnt,
                              void* d_out, int out_size, void* d_ws, size_t ws_size,
                              hipStream_t stream) {
    const float* x_geo = (const float*)d_in[0];
    const float* x_col = (const float*)d_in[1];
    const float* w0    = (const float*)d_in[2];
    const float* w_e1  = (const float*)d_in[3];
    const float* g_e1  = (const float*)d_in[4];
    const float* b_e1  = (const float*)d_in[5];
    const float* w2    = (const float*)d_in[6];
    const float* w_e2  = (const float*)d_in[7];
    const float* g_e2  = (const float*)d_in[8];
    const float* b_e2  = (const float*)d_in[9];
    const int* m1 = (const int*)d_in[10];
    const int* m2 = (const int*)d_in[12];
    const int* m3 = (const int*)d_in[14];
    const int* m4 = (const int*)d_in[16];

    const int n_vox = in_sizes[0];
    const int nc2 = in_sizes[10] / 125;
    const int nc4 = in_sizes[14] / 27;
    (void)out_size; (void)ws_size; (void)n_in_cnt;

    char* p = (char*)d_ws;
    auto alloc = [&](size_t bytes) -> char* {
        char* r = p;
        p += (bytes + 255) & ~(size_t)255;
        return r;
    };
    float* stats = (float*)alloc(8 * 512 * sizeof(float));
    __hip_bfloat16* x0 = (__hip_bfloat16*)alloc((size_t)(n_vox + 1) * 4 * 2);
    __hip_bfloat16* A  = (__hip_bfloat16*)alloc((size_t)(nc2 + 1) * 32 * 2);
    __hip_bfloat16* B  = (__hip_bfloat16*)alloc((size_t)(nc2 + 1) * 32 * 2);
    __hip_bfloat16* Cb = (__hip_bfloat16*)alloc((size_t)(nc2 + 1) * 32 * 2);
    __hip_bfloat16* D  = (__hip_bfloat16*)alloc((size_t)(nc4 + 1) * 64 * 2);
    __hip_bfloat16* E  = (__hip_bfloat16*)alloc((size_t)(nc4 + 1) * 64 * 2);
    __hip_bfloat16* Fb = (__hip_bfloat16*)alloc((size_t)(nc4 + 1) * 64 * 2);

    const long long sz_stem = 16LL * 2 * 512;
    const long long sz_e1   = 28LL * 2 * 512;
    const long long sz_c2   = 28LL * 4 * 512;
    const long long sz_e2   = 56LL * 4 * 512;
    const long long wf_total = sz_stem + 4 * sz_e1 + sz_c2 + 4 * sz_e2;
    __hip_bfloat16* Wf = (__hip_bfloat16*)alloc((size_t)wf_total * 2);

    ProArgs pa;
    long long cur = 0;
    auto seg = [&](int i, const float* W, int K, int CIN, int COUT, long long n) {
        pa.s[i].W = W; pa.s[i].K = K; pa.s[i].CIN = CIN; pa.s[i].COUT = COUT;
        pa.s[i].lgc = (CIN == 4) ? 2 : (CIN == 32) ? 5 : 6;
        pa.s[i].lgnt = (COUT == 32) ? 1 : 2;
        pa.s[i].begin = cur; pa.s[i].end = cur + n; cur += n;
    };
    seg(0, w0, 125, 4, 32, sz_stem);
    for (int i = 0; i < 4; ++i)
        seg(1 + i, w_e1 + (size_t)i * 27 * 32 * 32, 27, 32, 32, sz_e1);
    seg(5, w2, 27, 32, 64, sz_c2);
    for (int i = 0; i < 4; ++i)
        seg(6 + i, w_e2 + (size_t)i * 27 * 64 * 64, 27, 64, 64, sz_e2);

    long long off_e1[4], off_e2[4];
    cur = sz_stem;
    for (int i = 0; i < 4; ++i) { off_e1[i] = cur; cur += sz_e1; }
    long long off_c2 = cur; cur += sz_c2;
    for (int i = 0; i < 4; ++i) { off_e2[i] = cur; cur += sz_e2; }

    pa.geo = x_geo; pa.col = x_col; pa.x0 = x0; pa.n_vox = n_vox;
    pa.stats = stats;
    pa.pads[0] = x0 + (size_t)n_vox * 4; pa.padn[0] = 4;
    pa.pads[1] = A + (size_t)nc2 * 32;   pa.padn[1] = 32;
    pa.pads[2] = B + (size_t)nc2 * 32;   pa.padn[2] = 32;
    pa.pads[3] = D + (size_t)nc4 * 64;   pa.padn[3] = 64;
    pa.pads[4] = E + (size_t)nc4 * 64;   pa.padn[4] = 64;
    pa.wf_total = wf_total;
    pa.pro_total = wf_total + n_vox + 4096 + (4 + 32 + 32 + 64 + 64);
    pa.Wf = Wf;
    pa.m1 = m1;
    pa.A = A;
    pa.nc2 = nc2;

    k_prologue<<<ceil_div((int)pa.pro_total, 256), 256, 0, stream>>>(pa);
    k_stem<<<ceil_div(nc2, 64), 256, 0, stream>>>(pa);

    // enc1: two BasicBlocks, 32ch on c2 (MT=4) — hybrid LDS+VGPR pipeline
    k_conv<32, 32, 4, 27, false><<<ceil_div(nc2, 64), 256, 0, stream>>>(
        A, Wf + off_e1[0], m2, B, stats + 0 * 512,
        nullptr, nullptr, nullptr, nc2, nc2);
    k_conv<32, 32, 4, 27, true><<<ceil_div(nc2, 64), 256, 0, stream>>>(
        B, Wf + off_e1[1], m2, Cb, stats + 1 * 512,
        stats + 0 * 512, g_e1 + 0, b_e1 + 0, nc2, nc2);
    k_bnres<32, false><<<ceil_div(nc2 * 4, 256), 256, 0, stream>>>(
        Cb, A, stats + 1 * 512, g_e1 + 32, b_e1 + 32, A, nc2);

    k_conv<32, 32, 4, 27, false><<<ceil_div(nc2, 64), 256, 0, stream>>>(
        A, Wf + off_e1[2], m2, B, stats + 2 * 512,
        nullptr, nullptr, nullptr, nc2, nc2);
    k_conv<32, 32, 4, 27, true><<<ceil_div(nc2, 64), 256, 0, stream>>>(
        B, Wf + off_e1[3], m2, Cb, stats + 3 * 512,
        stats + 2 * 512, g_e1 + 64, b_e1 + 64, nc2, nc2);
    k_bnres<32, false><<<ceil_div(nc2 * 4, 256), 256, 0, stream>>>(
        Cb, A, stats + 3 * 512, g_e1 + 96, b_e1 + 96, A, nc2);

    // conv2: 32ch@c2 -> 64ch@c4 (MT=1) — r23 async path
    k_conv<32, 64, 1, 27, false><<<ceil_div(nc4, 16), 256, 0, stream>>>(
        A, Wf + off_c2, m3, D, nullptr,
        nullptr, nullptr, nullptr, nc4, nc2);

    // enc2: two BasicBlocks, 64ch on c4 (MT=1) — r23 async path
    k_conv<64, 64, 1, 27, false><<<ceil_div(nc4, 16), 256, 0, stream>>>(
        D, Wf + off_e2[0], m4, E, stats + 4 * 512,
        nullptr, nullptr, nullptr, nc4, nc4);
    k_conv<64, 64, 1, 27, true><<<ceil_div(nc4, 16), 256, 0, stream>>>(
        E, Wf + off_e2[1], m4, Fb, stats + 5 * 512,
        stats + 4 * 512, g_e2 + 0, b_e2 + 0, nc4, nc4);
    k_bnres<64, false><<<ceil_div(nc4 * 8, 256), 256, 0, stream>>>(
        Fb, D, stats + 5 * 512, g_e2 + 64, b_e2 + 64, D, nc4);

    k_conv<64, 64, 1, 27, false><<<ceil_div(nc4, 16), 256, 0, stream>>>(
        D, Wf + off_e2[2], m4, E, stats + 6 * 512,
        nullptr, nullptr, nullptr, nc4, nc4);
    k_conv<64, 64, 1, 27, true><<<ceil_div(nc4, 16), 256, 0, stream>>>(
        E, Wf + off_e2[3], m4, Fb, stats + 7 * 512,
        stats + 6 * 512, g_e2 + 128, b_e2 + 128, nc4, nc4);
    k_bnres<64, true><<<ceil_div(nc4 * 8, 256), 256, 0, stream>>>(
        Fb, D, stats + 7 * 512, g_e2 + 192, b_e2 + 192, (float*)d_out, nc4);
}

// Round 15
// 305.597 us; speedup vs baseline: 1.0480x; 1.0480x over previous
//
#include <hip/hip_runtime.h>
#include <hip/hip_bf16.h>

// ---------------------------------------------------------------------------
// Sparse conv backbone, bf16 MFMA, round 25 = r23 revert (best: 306.9us) +
// r24's safe prologue pow2-shift fix.
// r24 post-mortem: hybrid D=4 (2x in-flight rows) REGRESSED enc1 -> the
// queue-depth model is falsified. Session-closed finding: enc1 is pinned at
// ~16 gather-line-requests/cycle chip-wide across FOUR structurally distinct
// schedules (direct / split-M / async-D2 / hybrid-D4, 4x in-flight range);
// LDS banks (r22), L2 locality (r23), occupancy (r11), latency depth (r24)
// each tested and eliminated by counters. Fixed per-request TA/L1 wall.
// Remaining lever (union-window gather dedup) needs per-block device-side
// sort of 1728 indices — cost > benefit at this size.
// This round locks in the best verified configuration:
//   * enc1 + conv2/enc2: r23's async queue-ordered D=2 k_conv (XCD swizzle,
//     S-dependent LDS slice swizzle, spread stats atomics).
//   * prologue: pow2 shifts for /CIN,%CIN,/NT (verified in r24).
// Expected: 305-308us, absmax 0.109375.
// ---------------------------------------------------------------------------

typedef float f4 __attribute__((ext_vector_type(4)));
typedef short short8 __attribute__((ext_vector_type(8)));
typedef short short4v __attribute__((ext_vector_type(4)));

#define BN_EPS 1e-5f

static inline int ceil_div(int a, int b) { return (a + b - 1) / b; }

static __device__ inline float btof(short s) {
    unsigned u = ((unsigned)(unsigned short)s) << 16;
    float f;
    __builtin_memcpy(&f, &u, 4);
    return f;
}
static __device__ inline short ftob(float f) {
    __hip_bfloat16 h = __float2bfloat16(f);
    short s;
    __builtin_memcpy(&s, &h, 2);
    return s;
}

// bijective XCD-aware swizzle (m204 form)
static __device__ inline int xcd_swz(int b, int nwg) {
    int q = nwg >> 3, rr = nwg & 7;
    int xcd = b & 7, pos = b >> 3;
    return (xcd < rr) ? (xcd * (q + 1) + pos)
                      : (rr * (q + 1) + (xcd - rr) * q + pos);
}

// async 16B global->LDS (per-lane global addr; wave-uniform LDS base)
static __device__ inline void gl_lds16(const void* g, void* l) {
    __builtin_amdgcn_global_load_lds(
        (const __attribute__((address_space(1))) void*)g,
        (__attribute__((address_space(3))) void*)l, 16, 0, 0);
}

template <int N>
static __device__ inline void s_wait_vmcnt() {
    static_assert(N >= 0 && N <= 20, "vmcnt range");
    if constexpr (N == 0) asm volatile("s_waitcnt vmcnt(0)" ::: "memory");
    else if constexpr (N == 8) asm volatile("s_waitcnt vmcnt(8)" ::: "memory");
    else if constexpr (N == 9) asm volatile("s_waitcnt vmcnt(9)" ::: "memory");
    else if constexpr (N == 18) asm volatile("s_waitcnt vmcnt(18)" ::: "memory");
    else if constexpr (N == 6) asm volatile("s_waitcnt vmcnt(6)" ::: "memory");
    else asm volatile("s_waitcnt vmcnt(4)" ::: "memory");
}

struct Seg {
    const float* W;
    long long begin, end;
    int K, CIN, COUT, lgc, lgnt;
};

struct ProArgs {
    Seg s[10];
    const float* geo;
    const float* col;
    __hip_bfloat16* x0;
    int n_vox;
    float* stats;
    __hip_bfloat16* pads[5];
    int padn[5];
    long long wf_total;
    long long pro_total;
    __hip_bfloat16* Wf;
    const int* m1;
    __hip_bfloat16* A;
    int nc2;
};

// ---------------- BN coefficient helper (NS slots: 8 for C=32, 4 for C=64) --
template <int C>
__device__ inline void bn_coef(const float* st, const float* g, const float* b,
                               int c, int n, float& sc, float& sh) {
    constexpr int NS = (C == 32) ? 8 : 4;
    float rn = 1.f / (float)n;
    float sum = 0.f, sq = 0.f;
#pragma unroll
    for (int s = 0; s < NS; ++s) {
        sum += st[(s * 2 + 0) * C + c];
        sq  += st[(s * 2 + 1) * C + c];
    }
    float mu = sum * rn;
    float inv = rsqrtf(sq * rn - mu * mu + BN_EPS);
    sc = inv * g[c];
    sh = b[c] - mu * sc;
}

// ---------------- prologue: pack weights + build x0 + zero stats/pads -------
__global__ __launch_bounds__(256) void k_prologue(ProArgs pa) {
    for (long long e = (long long)blockIdx.x * 256 + threadIdx.x; e < pa.pro_total;
         e += (long long)gridDim.x * 256) {
        if (e < pa.wf_total) {
            int si = 0;
#pragma unroll
            for (int i = 0; i < 10; ++i)
                if (e >= pa.s[i].end) si = i + 1;
            const Seg sg = pa.s[si];
            long long r = e - sg.begin;
            int j = (int)(r & 7);
            int lane = (int)((r >> 3) & 63);
            long long rest = r >> 9;
            int ntile = (int)(rest & ((1 << sg.lgnt) - 1));
            int chunk = (int)(rest >> sg.lgnt);
            int kd = chunk * 32 + ((lane >> 4) << 3) + j;
            int koff = kd >> sg.lgc;
            int ci = kd & (sg.CIN - 1);
            int n = ntile * 16 + (lane & 15);
            float v = (koff < sg.K) ? sg.W[((size_t)koff * sg.CIN + ci) * sg.COUT + n] : 0.f;
            pa.Wf[e] = __float2bfloat16(v);
            continue;
        }
        long long r = e - pa.wf_total;
        if (r < pa.n_vox) {
            int row = (int)r;
            pa.x0[row * 4 + 0] = __float2bfloat16(pa.geo[row]);
            pa.x0[row * 4 + 1] = __float2bfloat16(pa.col[row * 3 + 0]);
            pa.x0[row * 4 + 2] = __float2bfloat16(pa.col[row * 3 + 1]);
            pa.x0[row * 4 + 3] = __float2bfloat16(pa.col[row * 3 + 2]);
            continue;
        }
        r -= pa.n_vox;
        if (r < 4096) {
            pa.stats[r] = 0.f;
            continue;
        }
        r -= 4096;
#pragma unroll
        for (int i = 0; i < 5; ++i) {
            if (r < pa.padn[i]) {
                pa.pads[i][r] = __float2bfloat16(0.f);
                r = -1;
                break;
            }
            r -= pa.padn[i];
        }
    }
}

// ---------------- stem conv (CIN=4, COUT=32, K=125->128, relu) --------------
__global__ __launch_bounds__(256) void k_stem(ProArgs a) {
    const int t = threadIdx.x, w = t >> 6, lane = t & 63;
    const int quad = lane >> 4, ml = lane & 15;
    const int ntile = w & 1, mgroup = w >> 1;
    const int n_out = a.nc2, n_in = a.n_vox;
    const __hip_bfloat16* feat = a.x0;
    const __hip_bfloat16* Wf = a.Wf;   // stem at offset 0
    const int* in_map = a.m1;
    __hip_bfloat16* out = a.A;
    const int mb = blockIdx.x * 64 + mgroup * 32;
    const int m0 = mb + ml, m1 = mb + 16 + ml;
    const bool v0 = m0 < n_out, v1 = m1 < n_out;
    f4 acc0 = {0.f, 0.f, 0.f, 0.f};
    f4 acc1 = {0.f, 0.f, 0.f, 0.f};
#pragma unroll 2
    for (int chunk = 0; chunk < 16; ++chunk) {
        int k0 = chunk * 8 + quad * 2;
        int k1 = k0 + 1;
        int k0c = (k0 < 125) ? k0 : 0;   // weights zero for k>=125
        int k1c = (k1 < 125) ? k1 : 0;
        short8 b = *(const short8*)(Wf + ((size_t)(chunk * 2 + ntile) * 64 + lane) * 8);
        int ia = v0 ? in_map[(size_t)k0c * n_out + m0] : n_in;
        int ib = v0 ? in_map[(size_t)k1c * n_out + m0] : n_in;
        int ic = v1 ? in_map[(size_t)k0c * n_out + m1] : n_in;
        int id = v1 ? in_map[(size_t)k1c * n_out + m1] : n_in;
        short4v p0 = *(const short4v*)(feat + (size_t)ia * 4);
        short4v p1 = *(const short4v*)(feat + (size_t)ib * 4);
        short4v p2 = *(const short4v*)(feat + (size_t)ic * 4);
        short4v p3 = *(const short4v*)(feat + (size_t)id * 4);
        short8 a0, a1;
        a0[0] = p0[0]; a0[1] = p0[1]; a0[2] = p0[2]; a0[3] = p0[3];
        a0[4] = p1[0]; a0[5] = p1[1]; a0[6] = p1[2]; a0[7] = p1[3];
        a1[0] = p2[0]; a1[1] = p2[1]; a1[2] = p2[2]; a1[3] = p2[3];
        a1[4] = p3[0]; a1[5] = p3[1]; a1[6] = p3[2]; a1[7] = p3[3];
        acc0 = __builtin_amdgcn_mfma_f32_16x16x32_bf16(a0, b, acc0, 0, 0, 0);
        acc1 = __builtin_amdgcn_mfma_f32_16x16x32_bf16(a1, b, acc1, 0, 0, 0);
    }
    const int col = ntile * 16 + ml;
#pragma unroll
    for (int i = 0; i < 4; ++i) {
        int r0 = mb + quad * 4 + i;
        if (r0 < n_out)
            out[(size_t)r0 * 32 + col] = __float2bfloat16(fmaxf(acc0[i], 0.f));
        int r1 = mb + 16 + quad * 4 + i;
        if (r1 < n_out)
            out[(size_t)r1 * 32 + col] = __float2bfloat16(fmaxf(acc1[i], 0.f));
    }
}

// ---------------- async queue-ordered D=2 conv (all conv layers, r23) -------
// XCD-swizzled work id; gathers AND weights staged depth-2 in strict vmcnt
// queue order; LDS slice swizzle p = sl ^ ((row>>SW)&(S-1)), SW = S==4?1:0,
// applied identically on staging source and ds_read (both-sides involution).
template <int CIN, int COUT, int MT, int K, bool BNF>
__global__ __launch_bounds__(256, (CIN == 64) ? 3 : 4)
void k_conv(
    const __hip_bfloat16* __restrict__ feat,
    const __hip_bfloat16* __restrict__ Wf,
    const int* __restrict__ in_map,
    __hip_bfloat16* __restrict__ out,
    float* __restrict__ stats,
    const float* __restrict__ in_stats,
    const float* __restrict__ in_g,
    const float* __restrict__ in_b,
    int n_out, int n_in) {
    constexpr int NT = COUT / 16;
    constexpr int H = CIN / 32;
    constexpr int R = MT * 16;
    constexpr int KPW = (K + 3) / 4;
    constexpr int SP = COUT + 1;
    constexpr int S = CIN / 8;             // 16B slices per feature row
    constexpr int SW = (S == 4) ? 1 : 0;   // swizzle row-shift (bank-class fix)
    constexpr int RPI = 64 / S;            // rows per gload instr (1KB each)
    constexpr int NI = R / RPI;            // gload instrs per stage
    constexpr int NB = H * NT;             // bfrag 16B loads per stage
    constexpr int D = 2;                   // pipeline depth (gathers+weights)
    constexpr int WAIT_N = NI + 2 * NB;    // enc1:8  enc2:18  conv2:9
    constexpr int NSLOT = (COUT == 32) ? 8 : 4;   // stats partial slots
    constexpr int STAGE_B = R * CIN * 2;   // stage bytes per wave
    constexpr int STAGE_TOT = 4 * D * STAGE_B;
    constexpr int RED_B = 4 * R * SP * 4;
    constexpr int UNION_B = (STAGE_TOT > RED_B) ? STAGE_TOT : RED_B;

    __shared__ char smem[UNION_B + 2048 + 512];
    float* red  = (float*)smem;                     // aliases stage region
    float* sred = (float*)(smem + UNION_B);
    float* ibn  = (float*)(smem + UNION_B + 2048);

    const int t = threadIdx.x, w = t >> 6, lane = t & 63;
    const int quad = lane >> 4, ml = lane & 15;
    const int wb = xcd_swz((int)blockIdx.x, (int)gridDim.x);   // work id
    const int mb = wb * R;
    char* stw = smem + w * (D * STAGE_B);           // this wave's stage base
    const int srow = lane / S;                      // staging row-in-instr
    const int ssl = lane & (S - 1);                 // staging physical slice

    if constexpr (BNF) {
        if (t < CIN) {
            float sc, sh;
            bn_coef<CIN>(in_stats, in_g, in_b, t, n_in, sc, sh);
            ibn[t] = sc;
            ibn[CIN + t] = sh;
        }
        __syncthreads();
    }
    float scr[H][8], shr[H][8];
    if constexpr (BNF) {
#pragma unroll
        for (int h = 0; h < H; ++h)
#pragma unroll
            for (int j = 0; j < 8; ++j) {
                int ch = h * 32 + quad * 8 + j;
                scr[h][j] = ibn[ch];
                shr[h][j] = ibn[CIN + ch];
            }
    }

    int idxs[KPW][NI];
#pragma unroll
    for (int kk = 0; kk < KPW; ++kk) {
        const int k = kk * 4 + w;
        const int krow = (k < K) ? k : 0;
        const int* mk = in_map + (size_t)krow * n_out;
#pragma unroll
        for (int inst = 0; inst < NI; ++inst) {
            int m = mb + inst * RPI + srow;
            idxs[kk][inst] = (m < n_out) ? mk[m] : n_in;
        }
    }

    f4 acc[MT * NT];
#pragma unroll
    for (int i = 0; i < MT * NT; ++i) acc[i] = (f4){0.f, 0.f, 0.f, 0.f};

    short8 bf0[NB], bf1[NB];

    auto issue_stage = [&](int stg, int slot) {
#pragma unroll
        for (int inst = 0; inst < NI; ++inst) {
            int rg = inst * RPI + srow;
            int gsl = ssl ^ ((rg >> SW) & (S - 1));   // swizzled source slice
            const __hip_bfloat16* src =
                feat + (size_t)idxs[stg][inst] * CIN + gsl * 8;
            gl_lds16(src, stw + slot * STAGE_B + inst * 1024);
        }
    };
    auto issue_bf = [&](int stg, short8 (&bfc)[NB]) {
        const int k = stg * 4 + w;
#pragma unroll
        for (int h = 0; h < H; ++h)
#pragma unroll
            for (int nt = 0; nt < NT; ++nt)
                bfc[h * NT + nt] = *(const short8*)(
                    Wf + (((size_t)(k * H + h) * NT + nt) * 64 + lane) * 8);
    };

    issue_stage(0, 0);
    issue_bf(0, bf0);
    issue_stage(1, 1);
    issue_bf(1, bf1);
    __builtin_amdgcn_sched_barrier(0);

#pragma unroll
    for (int kk = 0; kk < KPW; ++kk) {
        s_wait_vmcnt<WAIT_N>();                // stage kk landed in LDS
        __builtin_amdgcn_sched_barrier(0);

        const int slot = kk & 1;
        short8 (&bfc)[NB] = (kk & 1) ? bf1 : bf0;

        int cidx[MT];
        if constexpr (BNF) {
#pragma unroll
            for (int mi = 0; mi < MT; ++mi) {
                if constexpr (RPI >= 16) {
                    cidx[mi] = __shfl(idxs[kk][(mi * 16) / RPI], ml * S);
                } else {
                    int a0 = __shfl(idxs[kk][0], (ml & 7) * S);
                    int a1 = __shfl(idxs[kk][NI - 1], (ml & 7) * S);
                    cidx[mi] = (ml < 8) ? a0 : a1;
                }
            }
        }

#pragma unroll
        for (int mi = 0; mi < MT; ++mi) {
#pragma unroll
            for (int h = 0; h < H; ++h) {
                const int p = (h * 4 + quad) ^ ((ml >> SW) & (S - 1));
                short8 a = *(const short8*)(
                    stw + slot * STAGE_B + ((mi * 16 + ml) * CIN + p * 8) * 2);
                if constexpr (BNF) {
                    const bool sent = (cidx[mi] == n_in);
#pragma unroll
                    for (int j = 0; j < 8; ++j) {
                        float f = btof(a[j]) * scr[h][j] + shr[h][j];
                        f = fmaxf(f, 0.f);
                        a[j] = sent ? (short)0 : ftob(f);
                    }
                }
#pragma unroll
                for (int nt = 0; nt < NT; ++nt)
                    acc[mi * NT + nt] = __builtin_amdgcn_mfma_f32_16x16x32_bf16(
                        a, bfc[h * NT + nt], acc[mi * NT + nt], 0, 0, 0);
            }
        }

        __builtin_amdgcn_sched_barrier(0);
        const int ns = (kk + 2 < KPW) ? (kk + 2) : 0;
        issue_stage(ns, slot);
        if (kk & 1) issue_bf(ns, bf1); else issue_bf(ns, bf0);
        __builtin_amdgcn_sched_barrier(0);
    }

#pragma unroll
    for (int i = 0; i < NB; ++i) {
        asm volatile("" ::"v"(bf0[i]));
        asm volatile("" ::"v"(bf1[i]));
    }

    s_wait_vmcnt<0>();
    __syncthreads();

#pragma unroll
    for (int mi = 0; mi < MT; ++mi)
#pragma unroll
        for (int nt = 0; nt < NT; ++nt)
#pragma unroll
            for (int i = 0; i < 4; ++i)
                red[((size_t)w * R + mi * 16 + quad * 4 + i) * SP + nt * 16 + ml] =
                    acc[mi * NT + nt][i];
    __syncthreads();

    constexpr int E = (R * COUT) / 256;
    constexpr int RSTEP = 256 / COUT;
    const int col = t % COUT;
    const int rg = t / COUT;
    float s = 0.f, s2 = 0.f;
#pragma unroll
    for (int i = 0; i < E; ++i) {
        int r = rg + i * RSTEP;
        float v = red[(0 * R + r) * SP + col] + red[(1 * R + r) * SP + col] +
                  red[(2 * R + r) * SP + col] + red[(3 * R + r) * SP + col];
        s += v;
        s2 += v * v;
        int grow = mb + r;
        if (grow < n_out) out[(size_t)grow * COUT + col] = __float2bfloat16(v);
    }

    if (stats) {
        sred[t] = s;
        sred[256 + t] = s2;
        __syncthreads();
        if (t < 2 * COUT) {
            int c = t % COUT;
            int which = t / COUT;   // 0 = sum, 1 = sumsq
            float v = 0.f;
#pragma unroll
            for (int j = 0; j < RSTEP; ++j) v += sred[which * 256 + j * COUT + c];
            atomicAdd(&stats[((wb & (NSLOT - 1)) * 2 + which) * COUT + c], v);
        }
    }
}

// ---------------- BN residual apply ----------------
template <int C, bool F32OUT>
__global__ __launch_bounds__(256) void k_bnres(
    const __hip_bfloat16* __restrict__ y, const __hip_bfloat16* __restrict__ res,
    const float* __restrict__ st, const float* __restrict__ g,
    const float* __restrict__ b, void* outp, int n) {
    __shared__ float ibn[2 * C];
    const int t = threadIdx.x;
    if (t < C) {
        float sc, sh;
        bn_coef<C>(st, g, b, t, n, sc, sh);
        ibn[t] = sc;
        ibn[C + t] = sh;
    }
    __syncthreads();
    long long tot = (long long)n * (C / 8);
    long long i = (long long)blockIdx.x * 256 + t;
    if (i >= tot) return;
    int c0 = (int)(i % (C / 8)) * 8;
    short8 v = *(const short8*)(y + i * 8);
    short8 r = *(const short8*)(res + i * 8);
    if constexpr (F32OUT) {
        float* out = (float*)outp;
        f4 o0, o1;
#pragma unroll
        for (int j = 0; j < 8; ++j) {
            float f = btof(v[j]) * ibn[c0 + j] + ibn[C + c0 + j] + btof(r[j]);
            f = fmaxf(f, 0.f);
            if (j < 4) o0[j] = f; else o1[j - 4] = f;
        }
        *(f4*)(out + i * 8) = o0;
        *(f4*)(out + i * 8 + 4) = o1;
    } else {
        __hip_bfloat16* out = (__hip_bfloat16*)outp;
        short8 o;
#pragma unroll
        for (int j = 0; j < 8; ++j) {
            float f = btof(v[j]) * ibn[c0 + j] + ibn[C + c0 + j] + btof(r[j]);
            o[j] = ftob(fmaxf(f, 0.f));
        }
        *(short8*)(out + i * 8) = o;
    }
}

// ---------------------------------------------------------------------------
extern "C" void kernel_launch(void* const* d_in, const int* in_sizes, int n_in_cnt,
                              void* d_out, int out_size, void* d_ws, size_t ws_size,
                              hipStream_t stream) {
    const float* x_geo = (const float*)d_in[0];
    const float* x_col = (const float*)d_in[1];
    const float* w0    = (const float*)d_in[2];
    const float* w_e1  = (const float*)d_in[3];
    const float* g_e1  = (const float*)d_in[4];
    const float* b_e1  = (const float*)d_in[5];
    const float* w2    = (const float*)d_in[6];
    const float* w_e2  = (const float*)d_in[7];
    const float* g_e2  = (const float*)d_in[8];
    const float* b_e2  = (const float*)d_in[9];
    const int* m1 = (const int*)d_in[10];
    const int* m2 = (const int*)d_in[12];
    const int* m3 = (const int*)d_in[14];
    const int* m4 = (const int*)d_in[16];

    const int n_vox = in_sizes[0];
    const int nc2 = in_sizes[10] / 125;
    const int nc4 = in_sizes[14] / 27;
    (void)out_size; (void)ws_size; (void)n_in_cnt;

    char* p = (char*)d_ws;
    auto alloc = [&](size_t bytes) -> char* {
        char* r = p;
        p += (bytes + 255) & ~(size_t)255;
        return r;
    };
    float* stats = (float*)alloc(8 * 512 * sizeof(float));
    __hip_bfloat16* x0 = (__hip_bfloat16*)alloc((size_t)(n_vox + 1) * 4 * 2);
    __hip_bfloat16* A  = (__hip_bfloat16*)alloc((size_t)(nc2 + 1) * 32 * 2);
    __hip_bfloat16* B  = (__hip_bfloat16*)alloc((size_t)(nc2 + 1) * 32 * 2);
    __hip_bfloat16* Cb = (__hip_bfloat16*)alloc((size_t)(nc2 + 1) * 32 * 2);
    __hip_bfloat16* D  = (__hip_bfloat16*)alloc((size_t)(nc4 + 1) * 64 * 2);
    __hip_bfloat16* E  = (__hip_bfloat16*)alloc((size_t)(nc4 + 1) * 64 * 2);
    __hip_bfloat16* Fb = (__hip_bfloat16*)alloc((size_t)(nc4 + 1) * 64 * 2);

    const long long sz_stem = 16LL * 2 * 512;
    const long long sz_e1   = 28LL * 2 * 512;
    const long long sz_c2   = 28LL * 4 * 512;
    const long long sz_e2   = 56LL * 4 * 512;
    const long long wf_total = sz_stem + 4 * sz_e1 + sz_c2 + 4 * sz_e2;
    __hip_bfloat16* Wf = (__hip_bfloat16*)alloc((size_t)wf_total * 2);

    ProArgs pa;
    long long cur = 0;
    auto seg = [&](int i, const float* W, int K, int CIN, int COUT, long long n) {
        pa.s[i].W = W; pa.s[i].K = K; pa.s[i].CIN = CIN; pa.s[i].COUT = COUT;
        pa.s[i].lgc = (CIN == 4) ? 2 : (CIN == 32) ? 5 : 6;
        pa.s[i].lgnt = (COUT == 32) ? 1 : 2;
        pa.s[i].begin = cur; pa.s[i].end = cur + n; cur += n;
    };
    seg(0, w0, 125, 4, 32, sz_stem);
    for (int i = 0; i < 4; ++i)
        seg(1 + i, w_e1 + (size_t)i * 27 * 32 * 32, 27, 32, 32, sz_e1);
    seg(5, w2, 27, 32, 64, sz_c2);
    for (int i = 0; i < 4; ++i)
        seg(6 + i, w_e2 + (size_t)i * 27 * 64 * 64, 27, 64, 64, sz_e2);

    long long off_e1[4], off_e2[4];
    cur = sz_stem;
    for (int i = 0; i < 4; ++i) { off_e1[i] = cur; cur += sz_e1; }
    long long off_c2 = cur; cur += sz_c2;
    for (int i = 0; i < 4; ++i) { off_e2[i] = cur; cur += sz_e2; }

    pa.geo = x_geo; pa.col = x_col; pa.x0 = x0; pa.n_vox = n_vox;
    pa.stats = stats;
    pa.pads[0] = x0 + (size_t)n_vox * 4; pa.padn[0] = 4;
    pa.pads[1] = A + (size_t)nc2 * 32;   pa.padn[1] = 32;
    pa.pads[2] = B + (size_t)nc2 * 32;   pa.padn[2] = 32;
    pa.pads[3] = D + (size_t)nc4 * 64;   pa.padn[3] = 64;
    pa.pads[4] = E + (size_t)nc4 * 64;   pa.padn[4] = 64;
    pa.wf_total = wf_total;
    pa.pro_total = wf_total + n_vox + 4096 + (4 + 32 + 32 + 64 + 64);
    pa.Wf = Wf;
    pa.m1 = m1;
    pa.A = A;
    pa.nc2 = nc2;

    k_prologue<<<ceil_div((int)pa.pro_total, 256), 256, 0, stream>>>(pa);
    k_stem<<<ceil_div(nc2, 64), 256, 0, stream>>>(pa);

    // enc1: two BasicBlocks, 32ch on c2 (MT=4) — async + XCD swizzle
    k_conv<32, 32, 4, 27, false><<<ceil_div(nc2, 64), 256, 0, stream>>>(
        A, Wf + off_e1[0], m2, B, stats + 0 * 512,
        nullptr, nullptr, nullptr, nc2, nc2);
    k_conv<32, 32, 4, 27, true><<<ceil_div(nc2, 64), 256, 0, stream>>>(
        B, Wf + off_e1[1], m2, Cb, stats + 1 * 512,
        stats + 0 * 512, g_e1 + 0, b_e1 + 0, nc2, nc2);
    k_bnres<32, false><<<ceil_div(nc2 * 4, 256), 256, 0, stream>>>(
        Cb, A, stats + 1 * 512, g_e1 + 32, b_e1 + 32, A, nc2);

    k_conv<32, 32, 4, 27, false><<<ceil_div(nc2, 64), 256, 0, stream>>>(
        A, Wf + off_e1[2], m2, B, stats + 2 * 512,
        nullptr, nullptr, nullptr, nc2, nc2);
    k_conv<32, 32, 4, 27, true><<<ceil_div(nc2, 64), 256, 0, stream>>>(
        B, Wf + off_e1[3], m2, Cb, stats + 3 * 512,
        stats + 2 * 512, g_e1 + 64, b_e1 + 64, nc2, nc2);
    k_bnres<32, false><<<ceil_div(nc2 * 4, 256), 256, 0, stream>>>(
        Cb, A, stats + 3 * 512, g_e1 + 96, b_e1 + 96, A, nc2);

    // conv2: 32ch@c2 -> 64ch@c4 (MT=1) — async + XCD swizzle
    k_conv<32, 64, 1, 27, false><<<ceil_div(nc4, 16), 256, 0, stream>>>(
        A, Wf + off_c2, m3, D, nullptr,
        nullptr, nullptr, nullptr, nc4, nc2);

    // enc2: two BasicBlocks, 64ch on c4 (MT=1) — async + XCD swizzle
    k_conv<64, 64, 1, 27, false><<<ceil_div(nc4, 16), 256, 0, stream>>>(
        D, Wf + off_e2[0], m4, E, stats + 4 * 512,
        nullptr, nullptr, nullptr, nc4, nc4);
    k_conv<64, 64, 1, 27, true><<<ceil_div(nc4, 16), 256, 0, stream>>>(
        E, Wf + off_e2[1], m4, Fb, stats + 5 * 512,
        stats + 4 * 512, g_e2 + 0, b_e2 + 0, nc4, nc4);
    k_bnres<64, false><<<ceil_div(nc4 * 8, 256), 256, 0, stream>>>(
        Fb, D, stats + 5 * 512, g_e2 + 64, b_e2 + 64, D, nc4);

    k_conv<64, 64, 1, 27, false><<<ceil_div(nc4, 16), 256, 0, stream>>>(
        D, Wf + off_e2[2], m4, E, stats + 6 * 512,
        nullptr, nullptr, nullptr, nc4, nc4);
    k_conv<64, 64, 1, 27, true><<<ceil_div(nc4, 16), 256, 0, stream>>>(
        E, Wf + off_e2[3], m4, Fb, stats + 7 * 512,
        stats + 6 * 512, g_e2 + 128, b_e2 + 128, nc4, nc4);
    k_bnres<64, true><<<ceil_div(nc4 * 8, 256), 256, 0, stream>>>(
        Fb, D, stats + 7 * 512, g_e2 + 192, b_e2 + 192, (float*)d_out, nc4);
}